// Round 9
// baseline (2685.402 us; speedup 1.0000x reference)
//
#include <hip/hip_runtime.h>
#include <hip/hip_fp16.h>
#include <math.h>

#define D 512
#define NNODES 10000
#define NEDGES 80000
#define LAYERS 5
#define EPS 1e-5f

typedef _Float16 f16x8 __attribute__((ext_vector_type(8)));
typedef float f32x4 __attribute__((ext_vector_type(4)));

// ---------- fp16 helpers ----------
__device__ inline unsigned short f2h(float x) { return __half_as_ushort(__float2half(x)); }
__device__ inline float h2f(unsigned short u) { return __half2float(__ushort_as_half(u)); }
__device__ inline uint4 pack8(const unsigned short* v) {
  uint4 r;
  r.x = (unsigned)v[0] | ((unsigned)v[1] << 16);
  r.y = (unsigned)v[2] | ((unsigned)v[3] << 16);
  r.z = (unsigned)v[4] | ((unsigned)v[5] << 16);
  r.w = (unsigned)v[6] | ((unsigned)v[7] << 16);
  return r;
}
__device__ inline void unpack8(uint4 v, unsigned short* o) {
  o[0] = v.x & 0xffff; o[1] = v.x >> 16;
  o[2] = v.y & 0xffff; o[3] = v.y >> 16;
  o[4] = v.z & 0xffff; o[5] = v.z >> 16;
  o[6] = v.w & 0xffff; o[7] = v.w >> 16;
}

// ---------------------------------------------------------------------------
// A-format (activations): fp16 rows of 1024 B. Within each 64 B K-block
// (4 octets of 16 B), octet o sits at slot (o&3)^((r>>1)&3)  -> conflict-free
// quarter-wave ds_read_b128 from LDS.
// Weights: PLAIN [n=512][k=1024] fp16 rows (2048 B), unswizzled — read
// directly from global (L2-resident, 1 MB/mat) into registers.
// ---------------------------------------------------------------------------
__device__ inline int octA(int r, int o) {
  return ((o >> 2) << 6) + ((((o & 3) ^ ((r >> 1) & 3))) << 4);
}

// f32 [R][512] -> A-format fp16
__global__ __launch_bounds__(256) void toF16_k(const float* __restrict__ src,
                                               char* __restrict__ dst, int nOct) {
  for (long long i = (long long)blockIdx.x * 256 + threadIdx.x; i < nOct;
       i += (long long)gridDim.x * 256) {
    int row = (int)(i >> 6), oct = (int)(i & 63);
    const float* s = src + (size_t)row * 512 + oct * 8;
    float4 x0 = *(const float4*)s, x1 = *(const float4*)(s + 4);
    float xs[8] = {x0.x, x0.y, x0.z, x0.w, x1.x, x1.y, x1.z, x1.w};
    unsigned short h[8];
#pragma unroll
    for (int j = 0; j < 8; j++) h[j] = f2h(xs[j]);
    *(uint4*)(dst + (size_t)row * 1024 + octA(row, oct)) = pack8(h);
  }
}

// weight prep: W[1024][512] f32 (15 mats) -> WT[n=512][k=1024] plain fp16
__global__ __launch_bounds__(256) void wprep_k(const float* __restrict__ Wa,
                                               const float* __restrict__ Wn,
                                               const float* __restrict__ We,
                                               char* __restrict__ WT) {
  __shared__ float tile[64][65];
  int mat = blockIdx.z;
  const float* W = (mat < 5) ? Wa + (size_t)mat * 1024 * 512
                 : (mat < 10) ? Wn + (size_t)(mat - 5) * 1024 * 512
                              : We + (size_t)(mat - 10) * 1024 * 512;
  char* out = WT + (size_t)mat * 512 * 2048;
  int n0 = blockIdx.x * 64, k0 = blockIdx.y * 64;
  int t = threadIdx.x;
  int ty = t >> 2, tx = t & 3;
  const float* wr = W + (size_t)(k0 + ty) * 512 + n0 + tx * 16;
  float4 v0 = *(const float4*)(wr + 0), v1 = *(const float4*)(wr + 4);
  float4 v2 = *(const float4*)(wr + 8), v3 = *(const float4*)(wr + 12);
  float vv[16] = {v0.x, v0.y, v0.z, v0.w, v1.x, v1.y, v1.z, v1.w,
                  v2.x, v2.y, v2.z, v2.w, v3.x, v3.y, v3.z, v3.w};
#pragma unroll
  for (int j = 0; j < 16; j++) tile[ty][tx * 16 + j] = vv[j];
  __syncthreads();
#pragma unroll
  for (int p = 0; p < 2; p++) {
    int chunk = t + p * 256;
    int n = chunk >> 3, cc = chunk & 7;
    float xs[8];
#pragma unroll
    for (int j = 0; j < 8; j++) xs[j] = tile[cc * 8 + j][n];
    unsigned short h[8];
#pragma unroll
    for (int j = 0; j < 8; j++) h[j] = f2h(xs[j]);
    int ng = n0 + n;
    int kc = (k0 >> 3) + cc;   // octet index 0..127
    *(uint4*)(out + (size_t)ng * 2048 + kc * 16) = pack8(h);
  }
}

// ---------------------------------------------------------------------------
// CSR build over dst (dst fixed across layers)
// ---------------------------------------------------------------------------
__global__ __launch_bounds__(256) void hist_k(const int* __restrict__ dst, int* __restrict__ cnt) {
  int e = blockIdx.x * 256 + threadIdx.x;
  if (e < NEDGES) atomicAdd(&cnt[dst[e]], 1);
}

__global__ __launch_bounds__(256) void scan_k(const int* __restrict__ cnt,
                                              int* __restrict__ off, int* __restrict__ cur) {
  __shared__ int part[256];
  const int CH = (NNODES + 255) / 256;
  int t = threadIdx.x;
  int s = 0;
  int l0 = t * CH;
  for (int i = 0; i < CH; i++) {
    int idx = l0 + i;
    if (idx < NNODES) s += cnt[idx];
  }
  part[t] = s;
  __syncthreads();
  if (t == 0) {
    int acc = 0;
    for (int i = 0; i < 256; i++) { int v = part[i]; part[i] = acc; acc += v; }
  }
  __syncthreads();
  int acc = part[t];
  for (int i = 0; i < CH; i++) {
    int idx = l0 + i;
    if (idx < NNODES) { off[idx] = acc; cur[idx] = acc; acc += cnt[idx]; }
  }
  if (t == 255) off[NNODES] = acc;
}

__global__ __launch_bounds__(256) void scatter_k(const int* __restrict__ dst,
                                                 int* __restrict__ cur, int* __restrict__ eid) {
  int e = blockIdx.x * 256 + threadIdx.x;
  if (e < NEDGES) {
    int p = atomicAdd(&cur[dst[e]], 1);
    eid[p] = e;
  }
}

// ---------------------------------------------------------------------------
// GEMM: Y[R][512] = X@W. A: reg-staged global->VGPR->ds_write (2 LDS buffers,
// 8 KB each, compiler-tracked waits). B: direct L2->register loads, no LDS.
// One lgkmcnt(0)+s_barrier per 32-K window; zero manual vmcnt.
// ---------------------------------------------------------------------------
template<int KT, bool ACT, bool OUT_I, bool CMAX>
__global__ __launch_bounds__(256) void gemmI(const char* __restrict__ X1,
                                             const char* __restrict__ X2,
                                             const char* __restrict__ BW, int cb0,
                                             void* __restrict__ Yout, int R,
                                             const int* __restrict__ srcI,
                                             const int* __restrict__ dstI,
                                             const float* __restrict__ Na,
                                             float* __restrict__ part_p,
                                             float* __restrict__ part_r) {
  __shared__ char smem[32768];   // K-loop: 2 x 8 KB A buffers; epilogue: 32 KB stg
  const int tid = threadIdx.x;
  const int lane = tid & 63, wv = tid >> 6;
  const int NT = KT / 32;
  // bijective XCD chunking
  int flat = blockIdx.y * 4 + blockIdx.x;
  int total = gridDim.y * 4;
  int xcd = flat & 7, idx = flat >> 3;
  int q = total >> 3, rem = total & 7;
  int base = xcd * q + (xcd < rem ? xcd : rem);
  int f2 = base + idx;
  const int bn0 = (f2 & 3) * 128, bm0 = (f2 >> 2) * 128;
  const int r16 = lane & 15, g = lane >> 4;
  const int mo = (wv >> 1) * 64, no = (wv & 1) * 64;
  const int lr16 = lane >> 2, ls16 = (lane & 3) * 16;
  f32x4 acc[4][4];
#pragma unroll
  for (int i = 0; i < 4; i++)
#pragma unroll
    for (int j = 0; j < 4; j++) acc[i][j] = (f32x4){0.f, 0.f, 0.f, 0.f};

  // A fragment LDS offsets (within one 8 KB buffer)
  int offA[4];
#pragma unroll
  for (int mi = 0; mi < 4; mi++) {
    int row = mo + mi * 16 + r16;
    offA[mi] = row * 64 + ((g ^ ((row >> 1) & 3)) << 4);
  }
  // A global row bases (this thread stages 2 rows x 16 B per window)
  int g0 = bm0 + wv * 16 + lr16; if (g0 > R - 1) g0 = R - 1;
  int g1 = bm0 + 64 + wv * 16 + lr16; if (g1 > R - 1) g1 = R - 1;
  const char* a1_0 = X1 + (size_t)g0 * 1024 + ls16;
  const char* a1_1 = X1 + (size_t)g1 * 1024 + ls16;
  const char* a2_0 = (KT == 1024) ? X2 + (size_t)g0 * 1024 + ls16 : a1_0;
  const char* a2_1 = (KT == 1024) ? X2 + (size_t)g1 * 1024 + ls16 : a1_1;
  // B row bases (per-lane direct global loads)
  const char* pB[4];
#pragma unroll
  for (int ni = 0; ni < 4; ni++)
    pB[ni] = BW + (size_t)(bn0 + no + ni * 16 + r16) * 2048 + cb0 * 16 + g * 16;
  // LDS write offsets within a buffer
  const int w0 = wv * 1024 + lane * 16;
  const int w1 = (4 + wv) * 1024 + lane * 16;

  // ---- prologue: A(0) -> buf0; hold A(1); B(0) in regs ----
  {
    uint4 t00 = *(const uint4*)a1_0;
    uint4 t01 = *(const uint4*)a1_1;
    *(uint4*)(smem + w0) = t00;
    *(uint4*)(smem + w1) = t01;
  }
  uint4 ah0, ah1;
  {
    const char* b0 = (KT == 1024 && NT <= 16) ? a1_0 : a1_0;  // t2=1 always < 16
    (void)b0;
    ah0 = *(const uint4*)(a1_0 + 64);
    ah1 = *(const uint4*)(a1_1 + 64);
  }
  f16x8 bc[4];
#pragma unroll
  for (int ni = 0; ni < 4; ni++) bc[ni] = *(const f16x8*)(pB[ni]);
  asm volatile("s_waitcnt lgkmcnt(0)" ::: "memory");
  __builtin_amdgcn_s_barrier();
  __builtin_amdgcn_sched_barrier(0);

#pragma unroll 4
  for (int t = 0; t < NT; ++t) {
    // issue next-window B and next+1-window A loads (consumed later)
    f16x8 bn[4];
    uint4 an0 = make_uint4(0, 0, 0, 0), an1 = make_uint4(0, 0, 0, 0);
    if (t + 1 < NT) {
      int koff = (t + 1) * 64;
#pragma unroll
      for (int ni = 0; ni < 4; ni++) bn[ni] = *(const f16x8*)(pB[ni] + koff);
    } else {
#pragma unroll
      for (int ni = 0; ni < 4; ni++) bn[ni] = bc[ni];
    }
    if (t + 2 < NT) {
      int t2 = t + 2;
      const char* b0 = (KT == 1024 && t2 >= 16) ? a2_0 : a1_0;
      const char* b1 = (KT == 1024 && t2 >= 16) ? a2_1 : a1_1;
      int koff = (KT == 1024 ? (t2 & 15) : t2) * 64;
      an0 = *(const uint4*)(b0 + koff);
      an1 = *(const uint4*)(b1 + koff);
    }
    // compute window t from buf[t&1]
    const char* As = smem + (t & 1) * 8192;
    f16x8 a[4];
#pragma unroll
    for (int mi = 0; mi < 4; mi++) a[mi] = *(const f16x8*)(As + offA[mi]);
    __builtin_amdgcn_s_setprio(1);
#pragma unroll
    for (int mi = 0; mi < 4; mi++)
#pragma unroll
      for (int ni = 0; ni < 4; ni++)
        acc[mi][ni] = __builtin_amdgcn_mfma_f32_16x16x32_f16(a[mi], bc[ni], acc[mi][ni], 0, 0, 0);
    __builtin_amdgcn_s_setprio(0);
    // write A(t+1) into the other buffer, then barrier
    if (t + 1 < NT) {
      char* wbuf = smem + ((t + 1) & 1) * 8192;
      *(uint4*)(wbuf + w0) = ah0;
      *(uint4*)(wbuf + w1) = ah1;
      asm volatile("s_waitcnt lgkmcnt(0)" ::: "memory");
      __builtin_amdgcn_s_barrier();
      __builtin_amdgcn_sched_barrier(0);
    }
    ah0 = an0; ah1 = an1;
#pragma unroll
    for (int ni = 0; ni < 4; ni++) bc[ni] = bn[ni];
  }

  if (!OUT_I) {
    float* Y = (float*)Yout;
#pragma unroll
    for (int mi = 0; mi < 4; mi++)
#pragma unroll
      for (int j = 0; j < 4; j++) {
        int row = bm0 + mo + mi * 16 + g * 4 + j;
        if (row < R) {
#pragma unroll
          for (int ni = 0; ni < 4; ni++) {
            float v = acc[mi][ni][j];
            if (ACT) v = (v >= 0.f) ? v : 0.01f * v;
            Y[(size_t)row * 512 + bn0 + no + ni * 16 + r16] = v;
          }
        }
      }
  } else {
    // LDS-staged A-format epilogue, two 64-row halves; optional fused colmax
    float* stg = (float*)smem;
    const int rg = tid >> 5, cq = (tid & 31) * 4;   // CMAX decomposition
    float4 mp4 = make_float4(-1e30f, -1e30f, -1e30f, -1e30f);
    float4 mr4 = mp4;
#pragma unroll
    for (int h = 0; h < 2; h++) {
      __syncthreads();
      if ((wv >> 1) == h) {
#pragma unroll
        for (int mi = 0; mi < 4; mi++)
#pragma unroll
          for (int j = 0; j < 4; j++) {
            int rl = mi * 16 + g * 4 + j;
#pragma unroll
            for (int ni = 0; ni < 4; ni++) {
              float v = acc[mi][ni][j];
              if (ACT) v = (v >= 0.f) ? v : 0.01f * v;
              stg[rl * 128 + no + ni * 16 + r16] = v;
            }
          }
      }
      __syncthreads();
#pragma unroll
      for (int qq = 0; qq < 4; qq++) {
        int idx2 = tid + qq * 256;
        int rl = idx2 >> 4, oc = idx2 & 15;
        int grow = bm0 + h * 64 + rl;
        if (grow < R) {
          unsigned short hh[8];
#pragma unroll
          for (int j = 0; j < 8; j++) hh[j] = f2h(stg[rl * 128 + oc * 8 + j]);
          int oct = (bn0 >> 3) + oc;
          *(uint4*)((char*)Yout + (size_t)grow * 1024 + octA(grow, oct)) = pack8(hh);
        }
      }
      if (CMAX) {
#pragma unroll 4
        for (int r = rg * 8; r < rg * 8 + 8; r++) {
          int grow = bm0 + h * 64 + r;
          int d = dstI[grow], s = srcI[grow];
          float4 v = *(const float4*)&stg[r * 128 + cq];
          v.x = h2f(f2h(v.x)); v.y = h2f(f2h(v.y));
          v.z = h2f(f2h(v.z)); v.w = h2f(f2h(v.w));
          float4 nd = *(const float4*)&Na[(size_t)d * 512 + bn0 + cq];
          float4 ns = *(const float4*)&Na[(size_t)s * 512 + bn0 + cq];
          mp4.x = fmaxf(mp4.x, v.x + nd.x); mp4.y = fmaxf(mp4.y, v.y + nd.y);
          mp4.z = fmaxf(mp4.z, v.z + nd.z); mp4.w = fmaxf(mp4.w, v.w + nd.w);
          mr4.x = fmaxf(mr4.x, v.x + ns.x); mr4.y = fmaxf(mr4.y, v.y + ns.y);
          mr4.z = fmaxf(mr4.z, v.z + ns.z); mr4.w = fmaxf(mr4.w, v.w + ns.w);
        }
      }
    }
    if (CMAX) {
      __syncthreads();
      float* red = (float*)smem;  // [8][128] p, then [8][128] r
      *(float4*)&red[rg * 128 + cq] = mp4;
      *(float4*)&red[1024 + rg * 128 + cq] = mr4;
      __syncthreads();
      if (tid < 128) {
        float vp = -1e30f, vr = -1e30f;
#pragma unroll
        for (int gi = 0; gi < 8; gi++) {
          vp = fmaxf(vp, red[gi * 128 + tid]);
          vr = fmaxf(vr, red[1024 + gi * 128 + tid]);
        }
        int panel = f2 >> 2;
        part_p[(size_t)panel * 512 + bn0 + tid] = vp;
        part_r[(size_t)panel * 512 + bn0 + tid] = vr;
      }
    }
  }
}

// colmax reduce: 625 partial rows -> m = [mp[512] | mr[512]], grid 4 x 256
__global__ __launch_bounds__(256) void colmax_red_k(const float* __restrict__ part,
                                                    float* __restrict__ m) {
  int idx = blockIdx.x * 256 + threadIdx.x;  // 0..1023
  int c = idx & 511;
  const float* P = part + (size_t)(idx >> 9) * (625 * 512) + c;
  float v = -1e30f;
#pragma unroll 1
  for (int b = 0; b < 625; b += 5) {
    float v0 = P[(size_t)(b + 0) * 512], v1 = P[(size_t)(b + 1) * 512];
    float v2 = P[(size_t)(b + 2) * 512], v3 = P[(size_t)(b + 3) * 512];
    float v4 = P[(size_t)(b + 4) * 512];
    v = fmaxf(v, fmaxf(fmaxf(v0, v1), fmaxf(fmaxf(v2, v3), v4)));
  }
  m[idx] = v;
}

// ---------------------------------------------------------------------------
// aggblend: per node n (one wave): z,z2 in regs over CSR in-edges; reads fp16
// EaH; writes blend fp16 to blendH; tail writes z2I. 1-ahead prefetch.
// ---------------------------------------------------------------------------
__global__ __launch_bounds__(256) void aggblend_k(const char* __restrict__ EaH,
                                                  const float* __restrict__ Na,
                                                  const char* __restrict__ exI,
                                                  const char* __restrict__ nxI,
                                                  const int* __restrict__ src,
                                                  const int* __restrict__ off,
                                                  const int* __restrict__ eid,
                                                  const float* __restrict__ mp,
                                                  const float* __restrict__ mr,
                                                  char* __restrict__ blendH,
                                                  char* __restrict__ z2I) {
  const int w = threadIdx.x >> 6, o = threadIdx.x & 63;
  int n = blockIdx.x * 4 + w;
  if (n >= NNODES) return;
  float m_p[8], m_r[8], nd[8], xd[8], z[8], z2[8];
#pragma unroll
  for (int j = 0; j < 8; j++) {
    m_p[j] = mp[o * 8 + j];
    m_r[j] = mr[o * 8 + j];
    z[j] = 0.f; z2[j] = 0.f;
  }
  {
    const float* np = Na + (size_t)n * 512 + o * 8;
    float4 d0 = *(const float4*)np, d1 = *(const float4*)(np + 4);
    nd[0] = d0.x; nd[1] = d0.y; nd[2] = d0.z; nd[3] = d0.w;
    nd[4] = d1.x; nd[5] = d1.y; nd[6] = d1.z; nd[7] = d1.w;
    unsigned short hh[8];
    unpack8(*(const uint4*)(nxI + (size_t)n * 1024 + octA(n, o)), hh);
#pragma unroll
    for (int j = 0; j < 8; j++) xd[j] = h2f(hh[j]);
  }
  const int i0 = off[n], i1 = off[n + 1];
  if (i0 < i1) {
    int e = eid[i0];
    int s = src[e];
    uint4 cea = *(const uint4*)(EaH + (size_t)e * 1024 + octA(e, o));
    const float* ns = Na + (size_t)s * 512 + o * 8;
    float4 cs0 = *(const float4*)ns, cs1 = *(const float4*)(ns + 4);
    uint4 cx = *(const uint4*)(exI + (size_t)e * 1024 + octA(e, o));
    uint4 cn = *(const uint4*)(nxI + (size_t)s * 1024 + octA(s, o));
    for (int i = i0; i < i1; i++) {
      int en = 0, sn = 0;
      float4 ps0, ps1;
      uint4 pea, px, pn;
      const bool more = (i + 1 < i1);
      if (more) {
        en = eid[i + 1];
        sn = src[en];
        pea = *(const uint4*)(EaH + (size_t)en * 1024 + octA(en, o));
        const float* ns2 = Na + (size_t)sn * 512 + o * 8;
        ps0 = *(const float4*)ns2; ps1 = *(const float4*)(ns2 + 4);
        px = *(const uint4*)(exI + (size_t)en * 1024 + octA(en, o));
        pn = *(const uint4*)(nxI + (size_t)sn * 1024 + octA(sn, o));
      }
      unsigned short eh[8], xh[8], sh[8];
      unpack8(cea, eh);
      unpack8(cx, xh);
      unpack8(cn, sh);
      float sv[8] = {cs0.x, cs0.y, cs0.z, cs0.w, cs1.x, cs1.y, cs1.z, cs1.w};
      unsigned short bh[8];
#pragma unroll
      for (int j = 0; j < 8; j++) {
        float ev = h2f(eh[j]);
        float sp = ev + nd[j] - m_p[j];
        float sr = ev + sv[j] - m_r[j];
        float ap = __expf(sp);
        float xe = h2f(xh[j]);
        z[j] += ap;
        z2[j] += ap * xe;
        float u = sr - sp;
        float evx = __expf(-fabsf(u));
        float wpos = 1.f / (1.f + evx);
        float wr = (u >= 0.f) ? wpos : 1.f - wpos;
        float xs_ = h2f(sh[j]);
        bh[j] = f2h(wr * xs_ + (1.f - wr) * xd[j]);
      }
      *(uint4*)(blendH + (size_t)e * 1024 + octA(e, o)) = pack8(bh);
      if (more) {
        e = en; s = sn;
        cea = pea; cs0 = ps0; cs1 = ps1;
        cx = px; cn = pn;
      }
    }
  }
  unsigned short zh[8];
#pragma unroll
  for (int j = 0; j < 8; j++) zh[j] = f2h(z2[j] / (z[j] + EPS));
  *(uint4*)(z2I + (size_t)n * 1024 + octA(n, o)) = pack8(zh);
}

// node_conf = nx @ Wnc ([512,55])
__global__ __launch_bounds__(256) void nodeconf_k(const float* __restrict__ nx,
                                                  const float* __restrict__ Wnc,
                                                  float* __restrict__ out) {
  int w = threadIdx.x >> 6, lane = threadIdx.x & 63;
  int n = blockIdx.x * 4 + w;
  const float* r = nx + (size_t)n * D;
  if (lane < 55) {
    float acc = 0.f;
    for (int k = 0; k < D; k++) acc = fmaf(r[k], Wnc[k * 55 + lane], acc);
    out[(size_t)n * 55 + lane] = acc;
  }
}

// edge_conf = ex @ Wec ([512,2])
__global__ __launch_bounds__(256) void edgeconf_k(const float* __restrict__ ex,
                                                  const float* __restrict__ Wec,
                                                  float* __restrict__ out) {
  int w = threadIdx.x >> 6, lane = threadIdx.x & 63;
  int e = blockIdx.x * 4 + w;
  const float* r = ex + (size_t)e * D;
  float a0 = 0.f, a1 = 0.f;
#pragma unroll
  for (int j = 0; j < 8; j++) {
    int c = lane + j * 64;
    float x = r[c];
    a0 = fmaf(x, Wec[c * 2 + 0], a0);
    a1 = fmaf(x, Wec[c * 2 + 1], a1);
  }
#pragma unroll
  for (int off = 32; off; off >>= 1) {
    a0 += __shfl_down(a0, off);
    a1 += __shfl_down(a1, off);
  }
  if (lane == 0) { out[(size_t)e * 2 + 0] = a0; out[(size_t)e * 2 + 1] = a1; }
}

extern "C" void kernel_launch(void* const* d_in, const int* in_sizes, int n_in,
                              void* d_out, int out_size, void* d_ws, size_t ws_size,
                              hipStream_t stream) {
  const float* in_nx = (const float*)d_in[0];
  const float* in_ex = (const float*)d_in[1];
  const int* src = (const int*)d_in[2];
  const int* dst = (const int*)d_in[3];
  const float* Wa = (const float*)d_in[4];
  const float* Wn = (const float*)d_in[5];
  const float* We = (const float*)d_in[6];
  const float* Wnc = (const float*)d_in[7];
  const float* Wec = (const float*)d_in[8];

  float* out = (float*)d_out;
  float* o_nx = out;
  float* o_nc = o_nx + (size_t)NNODES * D;
  float* o_ex = o_nc + (size_t)NNODES * 55;
  float* o_ec = o_ex + (size_t)NEDGES * D;

  const size_t SZ_EH = (size_t)NEDGES * 1024;   // 80 MB fp16 edge rows
  const size_t SZ_NH = (size_t)NNODES * 1024;
  const size_t SZ_NF = (size_t)NNODES * 2048;
  const size_t MATSZ = (size_t)512 * 2048;      // 1 MB per weight mat
  char* w = (char*)d_ws;
  char* EaH = w;                                // fp16 Ea
  char* blendH = w + SZ_EH;                     // fp16 blend
  char* exA = w + 2 * SZ_EH;                    // exI ping
  char* nxA = w + 3 * SZ_EH;                    // nxI ping
  float* Na = (float*)(w + 3 * SZ_EH + SZ_NH);
  char* z2I = w + 3 * SZ_EH + SZ_NH + SZ_NF;
  float* mpf = (float*)(w + 3 * SZ_EH + 2 * SZ_NH + SZ_NF);  // [mp|mr]
  char* WT = w + 3 * SZ_EH + 2 * SZ_NH + SZ_NF + 8192;
  char* csr = WT + 15 * MATSZ;
  int* cnt = (int*)csr;
  int* offp = cnt + NNODES + 8;
  int* cur = offp + NNODES + 8;
  int* eid = cur + NNODES + 8;
  float* part_p = (float*)(eid + NEDGES);       // 625*512
  float* part_r = part_p + 625 * 512;

  char* exB = (char*)o_ex;   // fp16 ping inside f32 output regions
  char* nxB = (char*)o_nx;

  // one-time prep
  wprep_k<<<dim3(8, 16, 15), 256, 0, stream>>>(Wa, Wn, We, WT);
  toF16_k<<<2048, 256, 0, stream>>>(in_ex, exA, NEDGES * 64);
  toF16_k<<<2048, 256, 0, stream>>>(in_nx, nxA, NNODES * 64);
  hipMemsetAsync(cnt, 0, NNODES * sizeof(int), stream);
  hist_k<<<(NEDGES + 255) / 256, 256, 0, stream>>>(dst, cnt);
  scan_k<<<1, 256, 0, stream>>>(cnt, offp, cur);
  scatter_k<<<(NEDGES + 255) / 256, 256, 0, stream>>>(dst, cur, eid);

  dim3 gE(4, NEDGES / 128);           // (4, 625)
  dim3 gN(4, (NNODES + 127) / 128);   // (4, 79)

  for (int l = 0; l < LAYERS; l++) {
    const char* WaT = WT + (size_t)l * MATSZ;
    const char* WnT = WT + (size_t)(5 + l) * MATSZ;
    const char* WeT = WT + (size_t)(10 + l) * MATSZ;
    char* exCur = (l & 1) ? exB : exA;
    char* exNxt = (l & 1) ? exA : exB;
    char* nxCur = (l & 1) ? nxB : nxA;
    char* nxNxt = (l & 1) ? nxA : nxB;

    // Na = nx @ Wa_bot (f32), then EaH = fp16(ex @ Wa_top) with fused colmax
    gemmI<512, false, false, false><<<gN, 256, 0, stream>>>(
        nxCur, nullptr, WaT, 64, Na, NNODES, nullptr, nullptr, nullptr, nullptr, nullptr);
    gemmI<512, false, true, true><<<gE, 256, 0, stream>>>(
        exCur, nullptr, WaT, 0, EaH, NEDGES, src, dst, Na, part_p, part_r);

    colmax_red_k<<<4, 256, 0, stream>>>(part_p, mpf);

    aggblend_k<<<(NNODES + 3) / 4, 256, 0, stream>>>(EaH, Na, exCur, nxCur, src,
                                                     offp, eid, mpf, mpf + 512, blendH, z2I);

    // node update: nx' = act(concat(z2, nx) @ Wn)
    if (l < 4)
      gemmI<1024, true, true, false><<<gN, 256, 0, stream>>>(
          z2I, nxCur, WnT, 0, nxNxt, NNODES, nullptr, nullptr, nullptr, nullptr, nullptr);
    else
      gemmI<1024, true, false, false><<<gN, 256, 0, stream>>>(
          z2I, nxCur, WnT, 0, o_nx, NNODES, nullptr, nullptr, nullptr, nullptr, nullptr);

    // edge update: ex' = act(concat(blend, ex) @ We)
    if (l < 4)
      gemmI<1024, true, true, false><<<gE, 256, 0, stream>>>(
          blendH, exCur, WeT, 0, exNxt, NEDGES, nullptr, nullptr, nullptr, nullptr, nullptr);
    else
      gemmI<1024, true, false, false><<<gE, 256, 0, stream>>>(
          blendH, exCur, WeT, 0, o_ex, NEDGES, nullptr, nullptr, nullptr, nullptr, nullptr);
  }

  nodeconf_k<<<NNODES / 4, 256, 0, stream>>>(o_nx, Wnc, o_nc);
  edgeconf_k<<<NEDGES / 4, 256, 0, stream>>>(o_ex, Wec, o_ec);
}

// Round 10
// 1978.819 us; speedup vs baseline: 1.3571x; 1.3571x over previous
//
#include <hip/hip_runtime.h>
#include <hip/hip_fp16.h>
#include <math.h>

#define D 512
#define NNODES 10000
#define NEDGES 80000
#define LAYERS 5
#define EPS 1e-5f

typedef _Float16 f16x8 __attribute__((ext_vector_type(8)));
typedef float f32x4 __attribute__((ext_vector_type(4)));

// ---------- fp16 helpers ----------
__device__ inline unsigned short f2h(float x) { return __half_as_ushort(__float2half(x)); }
__device__ inline float h2f(unsigned short u) { return __half2float(__ushort_as_half(u)); }
__device__ inline uint4 pack8(const unsigned short* v) {
  uint4 r;
  r.x = (unsigned)v[0] | ((unsigned)v[1] << 16);
  r.y = (unsigned)v[2] | ((unsigned)v[3] << 16);
  r.z = (unsigned)v[4] | ((unsigned)v[5] << 16);
  r.w = (unsigned)v[6] | ((unsigned)v[7] << 16);
  return r;
}
__device__ inline void unpack8(uint4 v, unsigned short* o) {
  o[0] = v.x & 0xffff; o[1] = v.x >> 16;
  o[2] = v.y & 0xffff; o[3] = v.y >> 16;
  o[4] = v.z & 0xffff; o[5] = v.z >> 16;
  o[6] = v.w & 0xffff; o[7] = v.w >> 16;
}

__device__ inline void gload16(const void* g, void* l) {
  __builtin_amdgcn_global_load_lds((const __attribute__((address_space(1))) void*)g,
                                   (__attribute__((address_space(3))) void*)l, 16, 0, 0);
}

// ---------------------------------------------------------------------------
// A-format (activations AND hi-only weights): fp16 rows; activation row =
// 1024 B (K=512), weight row = 2048 B (K=1024). Within each 64 B K-block
// (4 octets of 16 B), octet o sits at slot (o&3)^((r>>1)&3).
// Quarter-wave ds_read_b128: 2 lanes per 16B bank-class -> conflict-free.
// ---------------------------------------------------------------------------
__device__ inline int octA(int r, int o) {
  return ((o >> 2) << 6) + ((((o & 3) ^ ((r >> 1) & 3))) << 4);
}

// f32 [R][512] -> A-format fp16
__global__ __launch_bounds__(256) void toF16_k(const float* __restrict__ src,
                                               char* __restrict__ dst, int nOct) {
  for (long long i = (long long)blockIdx.x * 256 + threadIdx.x; i < nOct;
       i += (long long)gridDim.x * 256) {
    int row = (int)(i >> 6), oct = (int)(i & 63);
    const float* s = src + (size_t)row * 512 + oct * 8;
    float4 x0 = *(const float4*)s, x1 = *(const float4*)(s + 4);
    float xs[8] = {x0.x, x0.y, x0.z, x0.w, x1.x, x1.y, x1.z, x1.w};
    unsigned short h[8];
#pragma unroll
    for (int j = 0; j < 8; j++) h[j] = f2h(xs[j]);
    *(uint4*)(dst + (size_t)row * 1024 + octA(row, oct)) = pack8(h);
  }
}

// weight prep: W[1024][512] f32 (15 mats) -> WT[n=512][k=1024] hi-only fp16
__global__ __launch_bounds__(256) void wprep_k(const float* __restrict__ Wa,
                                               const float* __restrict__ Wn,
                                               const float* __restrict__ We,
                                               char* __restrict__ WT) {
  __shared__ float tile[64][65];
  int mat = blockIdx.z;
  const float* W = (mat < 5) ? Wa + (size_t)mat * 1024 * 512
                 : (mat < 10) ? Wn + (size_t)(mat - 5) * 1024 * 512
                              : We + (size_t)(mat - 10) * 1024 * 512;
  char* out = WT + (size_t)mat * 512 * 2048;
  int n0 = blockIdx.x * 64, k0 = blockIdx.y * 64;
  int t = threadIdx.x;
  int ty = t >> 2, tx = t & 3;
  const float* wr = W + (size_t)(k0 + ty) * 512 + n0 + tx * 16;
  float4 v0 = *(const float4*)(wr + 0), v1 = *(const float4*)(wr + 4);
  float4 v2 = *(const float4*)(wr + 8), v3 = *(const float4*)(wr + 12);
  float vv[16] = {v0.x, v0.y, v0.z, v0.w, v1.x, v1.y, v1.z, v1.w,
                  v2.x, v2.y, v2.z, v2.w, v3.x, v3.y, v3.z, v3.w};
#pragma unroll
  for (int j = 0; j < 16; j++) tile[ty][tx * 16 + j] = vv[j];
  __syncthreads();
#pragma unroll
  for (int p = 0; p < 2; p++) {
    int chunk = t + p * 256;
    int n = chunk >> 3, cc = chunk & 7;
    float xs[8];
#pragma unroll
    for (int j = 0; j < 8; j++) xs[j] = tile[cc * 8 + j][n];
    unsigned short h[8];
#pragma unroll
    for (int j = 0; j < 8; j++) h[j] = f2h(xs[j]);
    int ng = n0 + n;
    int kc = (k0 >> 3) + cc;   // octet index 0..127
    *(uint4*)(out + (size_t)ng * 2048 + octA(ng, kc)) = pack8(h);
  }
}

// ---------------------------------------------------------------------------
// CSR build over dst (dst fixed across layers)
// ---------------------------------------------------------------------------
__global__ __launch_bounds__(256) void hist_k(const int* __restrict__ dst, int* __restrict__ cnt) {
  int e = blockIdx.x * 256 + threadIdx.x;
  if (e < NEDGES) atomicAdd(&cnt[dst[e]], 1);
}

__global__ __launch_bounds__(256) void scan_k(const int* __restrict__ cnt,
                                              int* __restrict__ off, int* __restrict__ cur) {
  __shared__ int part[256];
  const int CH = (NNODES + 255) / 256;
  int t = threadIdx.x;
  int s = 0;
  int l0 = t * CH;
  for (int i = 0; i < CH; i++) {
    int idx = l0 + i;
    if (idx < NNODES) s += cnt[idx];
  }
  part[t] = s;
  __syncthreads();
  if (t == 0) {
    int acc = 0;
    for (int i = 0; i < 256; i++) { int v = part[i]; part[i] = acc; acc += v; }
  }
  __syncthreads();
  int acc = part[t];
  for (int i = 0; i < CH; i++) {
    int idx = l0 + i;
    if (idx < NNODES) { off[idx] = acc; cur[idx] = acc; acc += cnt[idx]; }
  }
  if (t == 255) off[NNODES] = acc;
}

__global__ __launch_bounds__(256) void scatter_k(const int* __restrict__ dst,
                                                 int* __restrict__ cur, int* __restrict__ eid) {
  int e = blockIdx.x * 256 + threadIdx.x;
  if (e < NEDGES) {
    int p = atomicAdd(&cur[dst[e]], 1);
    eid[p] = e;
  }
}

// ---------------------------------------------------------------------------
// GEMM: Y[R][512] = X@W, fp16 x fp16-hi. 3-buffer ring, depth-2 prefetch,
// counted vmcnt(4) + raw s_barrier (T3+T4), setprio around MFMA (T5).
// (round-8 proven structure)
// ---------------------------------------------------------------------------
template<int KT, bool ACT, bool OUT_I, bool CMAX>
__global__ __launch_bounds__(256) void gemmI(const char* __restrict__ X1,
                                             const char* __restrict__ X2,
                                             const char* __restrict__ BW, int cb0,
                                             void* __restrict__ Yout, int R,
                                             const int* __restrict__ srcI,
                                             const int* __restrict__ dstI,
                                             const float* __restrict__ Na,
                                             float* __restrict__ part_p,
                                             float* __restrict__ part_r) {
  __shared__ char smem[49152];   // 3 x [As 8K | Bs 8K]
  const int tid = threadIdx.x;
  const int lane = tid & 63, wv = tid >> 6;
  const int NT = KT / 32;
  // bijective XCD chunking
  int flat = blockIdx.y * 4 + blockIdx.x;
  int total = gridDim.y * 4;
  int xcd = flat & 7, idx = flat >> 3;
  int q = total >> 3, rem = total & 7;
  int base = xcd * q + (xcd < rem ? xcd : rem);
  int f2 = base + idx;
  const int bn0 = (f2 & 3) * 128, bm0 = (f2 >> 2) * 128;
  const int r16 = lane & 15, g = lane >> 4;
  const int mo = (wv >> 1) * 64, no = (wv & 1) * 64;
  const int lr16 = lane >> 2, ls16 = (lane & 3) * 16;
  f32x4 acc[4][4];
#pragma unroll
  for (int i = 0; i < 4; i++)
#pragma unroll
    for (int j = 0; j < 4; j++) acc[i][j] = (f32x4){0.f, 0.f, 0.f, 0.f};

  // loop-invariant LDS fragment offsets (64 B rows, octA swizzle)
  int offA[4], offB[4];
#pragma unroll
  for (int mi = 0; mi < 4; mi++) {
    int row = mo + mi * 16 + r16;
    offA[mi] = row * 64 + ((g ^ ((row >> 1) & 3)) << 4);
  }
#pragma unroll
  for (int ni = 0; ni < 4; ni++) {
    int row = no + ni * 16 + r16;
    offB[ni] = row * 64 + ((g ^ ((row >> 1) & 3)) << 4);
  }

  // staging pointers (advance +64 B per stage)
  const char* pA0;
  const char* pA1;
  const char* pB0;
  const char* pB1;
  {
    int g0 = bm0 + wv * 16 + lr16; if (g0 > R - 1) g0 = R - 1;
    int g1 = bm0 + (4 + wv) * 16 + lr16; if (g1 > R - 1) g1 = R - 1;
    pA0 = X1 + (size_t)g0 * 1024 + ls16;
    pA1 = X1 + (size_t)g1 * 1024 + ls16;
    int n0r = bn0 + wv * 16 + lr16;
    int n1r = bn0 + (4 + wv) * 16 + lr16;
    pB0 = BW + (size_t)n0r * 2048 + cb0 * 16 + ls16;
    pB1 = BW + (size_t)n1r * 2048 + cb0 * 16 + ls16;
  }

  int us = 0;  // next stage index to issue
#define STAGE()                                                 \
  {                                                             \
    char* sb = smem + (us % 3) * 16384;                         \
    gload16(pA0, sb + wv * 1024);                               \
    gload16(pA1, sb + (4 + wv) * 1024);                         \
    gload16(pB0, sb + 8192 + wv * 1024);                        \
    gload16(pB1, sb + 8192 + (4 + wv) * 1024);                  \
    pA0 += 64; pA1 += 64; pB0 += 64; pB1 += 64;                 \
    us++;                                                       \
  }

  STAGE();   // stage 0
  STAGE();   // stage 1  (8 loads in flight)
  for (int t = 0; t < NT; ++t) {
    if (t + 1 < NT) {
      asm volatile("s_waitcnt vmcnt(4)" ::: "memory");   // oldest stage landed
    } else {
      asm volatile("s_waitcnt vmcnt(0)" ::: "memory");
    }
    __builtin_amdgcn_s_barrier();                        // all waves: buf t ready
    if (us < NT) {
      if (KT == 1024 && us == 16) {
        int g0 = bm0 + wv * 16 + lr16; if (g0 > R - 1) g0 = R - 1;
        int g1 = bm0 + (4 + wv) * 16 + lr16; if (g1 > R - 1) g1 = R - 1;
        pA0 = X2 + (size_t)g0 * 1024 + ls16;
        pA1 = X2 + (size_t)g1 * 1024 + ls16;
      }
      STAGE();
    }
    const char* As = smem + (t % 3) * 16384;
    const char* Bs = As + 8192;
    f16x8 a[4], b[4];
#pragma unroll
    for (int mi = 0; mi < 4; mi++) a[mi] = *(const f16x8*)(As + offA[mi]);
#pragma unroll
    for (int ni = 0; ni < 4; ni++) b[ni] = *(const f16x8*)(Bs + offB[ni]);
    __builtin_amdgcn_s_setprio(1);
#pragma unroll
    for (int mi = 0; mi < 4; mi++)
#pragma unroll
      for (int ni = 0; ni < 4; ni++)
        acc[mi][ni] = __builtin_amdgcn_mfma_f32_16x16x32_f16(a[mi], b[ni], acc[mi][ni], 0, 0, 0);
    __builtin_amdgcn_s_setprio(0);
  }
#undef STAGE

  if (!OUT_I) {
    float* Y = (float*)Yout;
#pragma unroll
    for (int mi = 0; mi < 4; mi++)
#pragma unroll
      for (int j = 0; j < 4; j++) {
        int row = bm0 + mo + mi * 16 + g * 4 + j;
        if (row < R) {
#pragma unroll
          for (int ni = 0; ni < 4; ni++) {
            float v = acc[mi][ni][j];
            if (ACT) v = (v >= 0.f) ? v : 0.01f * v;
            Y[(size_t)row * 512 + bn0 + no + ni * 16 + r16] = v;
          }
        }
      }
  } else {
    // LDS-staged A-format epilogue, two 64-row halves; optional fused colmax
    float* stg = (float*)smem;
    const int rg = tid >> 5, cq = (tid & 31) * 4;   // CMAX decomposition
    float4 mp4 = make_float4(-1e30f, -1e30f, -1e30f, -1e30f);
    float4 mr4 = mp4;
#pragma unroll
    for (int h = 0; h < 2; h++) {
      __syncthreads();
      if ((wv >> 1) == h) {
#pragma unroll
        for (int mi = 0; mi < 4; mi++)
#pragma unroll
          for (int j = 0; j < 4; j++) {
            int rl = mi * 16 + g * 4 + j;
#pragma unroll
            for (int ni = 0; ni < 4; ni++) {
              float v = acc[mi][ni][j];
              if (ACT) v = (v >= 0.f) ? v : 0.01f * v;
              stg[rl * 128 + no + ni * 16 + r16] = v;
            }
          }
      }
      __syncthreads();
#pragma unroll
      for (int qq = 0; qq < 4; qq++) {
        int idx2 = tid + qq * 256;
        int rl = idx2 >> 4, oc = idx2 & 15;
        int grow = bm0 + h * 64 + rl;
        if (grow < R) {
          unsigned short hh[8];
#pragma unroll
          for (int j = 0; j < 8; j++) hh[j] = f2h(stg[rl * 128 + oc * 8 + j]);
          int oct = (bn0 >> 3) + oc;
          *(uint4*)((char*)Yout + (size_t)grow * 1024 + octA(grow, oct)) = pack8(hh);
        }
      }
      if (CMAX) {
#pragma unroll 2
        for (int r = rg * 8; r < rg * 8 + 8; r++) {
          int grow = bm0 + h * 64 + r;
          int d = dstI[grow], s = srcI[grow];
          float4 v = *(const float4*)&stg[r * 128 + cq];
          v.x = h2f(f2h(v.x)); v.y = h2f(f2h(v.y));
          v.z = h2f(f2h(v.z)); v.w = h2f(f2h(v.w));
          float4 nd = *(const float4*)&Na[(size_t)d * 512 + bn0 + cq];
          float4 ns = *(const float4*)&Na[(size_t)s * 512 + bn0 + cq];
          mp4.x = fmaxf(mp4.x, v.x + nd.x); mp4.y = fmaxf(mp4.y, v.y + nd.y);
          mp4.z = fmaxf(mp4.z, v.z + nd.z); mp4.w = fmaxf(mp4.w, v.w + nd.w);
          mr4.x = fmaxf(mr4.x, v.x + ns.x); mr4.y = fmaxf(mr4.y, v.y + ns.y);
          mr4.z = fmaxf(mr4.z, v.z + ns.z); mr4.w = fmaxf(mr4.w, v.w + ns.w);
        }
      }
    }
    if (CMAX) {
      __syncthreads();
      float* red = (float*)smem;  // [8][128] p, then [8][128] r
      *(float4*)&red[rg * 128 + cq] = mp4;
      *(float4*)&red[1024 + rg * 128 + cq] = mr4;
      __syncthreads();
      if (tid < 128) {
        float vp = -1e30f, vr = -1e30f;
#pragma unroll
        for (int gi = 0; gi < 8; gi++) {
          vp = fmaxf(vp, red[gi * 128 + tid]);
          vr = fmaxf(vr, red[1024 + gi * 128 + tid]);
        }
        int panel = f2 >> 2;
        part_p[(size_t)panel * 512 + bn0 + tid] = vp;
        part_r[(size_t)panel * 512 + bn0 + tid] = vr;
      }
    }
  }
}

// colmax reduce stage 1: 625 rows -> 5 segment rows (of 1024 cols: [p|r])
__global__ __launch_bounds__(256) void colmax_red1_k(const float* __restrict__ part,
                                                     float* __restrict__ part2) {
  int bx = blockIdx.x;             // 0..19: seg = bx/4, quarter = bx%4
  int seg = bx >> 2;
  int idx = (bx & 3) * 256 + threadIdx.x;   // 0..1023
  int c = idx & 511;
  const float* P = part + (size_t)(idx >> 9) * (625 * 512) + c;
  int b0 = seg * 125, b1 = b0 + 125;
  float v = -1e30f;
#pragma unroll 1
  for (int b = b0; b < b1; b += 5) {
    float v0 = P[(size_t)(b + 0) * 512], v1 = P[(size_t)(b + 1) * 512];
    float v2 = P[(size_t)(b + 2) * 512], v3 = P[(size_t)(b + 3) * 512];
    float v4 = P[(size_t)(b + 4) * 512];
    v = fmaxf(v, fmaxf(fmaxf(v0, v1), fmaxf(fmaxf(v2, v3), v4)));
  }
  part2[(size_t)seg * 1024 + idx] = v;
}

// colmax reduce stage 2: 5 segment rows -> m = [mp[512] | mr[512]]
__global__ __launch_bounds__(256) void colmax_red2_k(const float* __restrict__ part2,
                                                     float* __restrict__ m) {
  int idx = blockIdx.x * 256 + threadIdx.x;  // 0..1023
  float v = part2[idx];
#pragma unroll
  for (int s = 1; s < 5; s++) v = fmaxf(v, part2[(size_t)s * 1024 + idx]);
  m[idx] = v;
}

// ---------------------------------------------------------------------------
// aggblend: per node n (one wave): z,z2 in regs over CSR in-edges; reads fp16
// EaH; writes blend fp16 to blendH; tail writes z2I. Depth-2 pipeline (3 slots).
// ---------------------------------------------------------------------------
__global__ __launch_bounds__(256) void aggblend_k(const char* __restrict__ EaH,
                                                  const float* __restrict__ Na,
                                                  const char* __restrict__ exI,
                                                  const char* __restrict__ nxI,
                                                  const int* __restrict__ src,
                                                  const int* __restrict__ off,
                                                  const int* __restrict__ eid,
                                                  const float* __restrict__ mp,
                                                  const float* __restrict__ mr,
                                                  char* __restrict__ blendH,
                                                  char* __restrict__ z2I) {
  const int w = threadIdx.x >> 6, o = threadIdx.x & 63;
  int n = blockIdx.x * 4 + w;
  if (n >= NNODES) return;
  float m_p[8], m_r[8], nd[8], xd[8], z[8], z2[8];
#pragma unroll
  for (int j = 0; j < 8; j++) {
    m_p[j] = mp[o * 8 + j];
    m_r[j] = mr[o * 8 + j];
    z[j] = 0.f; z2[j] = 0.f;
  }
  {
    const float* np = Na + (size_t)n * 512 + o * 8;
    float4 d0 = *(const float4*)np, d1 = *(const float4*)(np + 4);
    nd[0] = d0.x; nd[1] = d0.y; nd[2] = d0.z; nd[3] = d0.w;
    nd[4] = d1.x; nd[5] = d1.y; nd[6] = d1.z; nd[7] = d1.w;
    unsigned short hh[8];
    unpack8(*(const uint4*)(nxI + (size_t)n * 1024 + octA(n, o)), hh);
#pragma unroll
    for (int j = 0; j < 8; j++) xd[j] = h2f(hh[j]);
  }
  const int i0 = off[n], i1 = off[n + 1];
  const int cnt = i1 - i0;
  if (cnt > 0) {
#define LOADE(ii, e_, ea_, x_, nn_, s0_, s1_)                        \
    {                                                                \
      e_ = eid[ii];                                                  \
      int s_ = src[e_];                                              \
      ea_ = *(const uint4*)(EaH + (size_t)e_ * 1024 + octA(e_, o));  \
      x_  = *(const uint4*)(exI + (size_t)e_ * 1024 + octA(e_, o));  \
      nn_ = *(const uint4*)(nxI + (size_t)s_ * 1024 + octA(s_, o));  \
      const float* nsp_ = Na + (size_t)s_ * 512 + o * 8;             \
      s0_ = *(const float4*)nsp_;                                    \
      s1_ = *(const float4*)(nsp_ + 4);                              \
    }
    int eA, eB;
    uint4 eaA, xA, nA, eaB, xB, nB;
    float4 sA0, sA1, sB0, sB1;
    LOADE(i0, eA, eaA, xA, nA, sA0, sA1);
    if (cnt > 1) {
      LOADE(i0 + 1, eB, eaB, xB, nB, sB0, sB1);
    } else {
      eB = eA; eaB = eaA; xB = xA; nB = nA; sB0 = sA0; sB1 = sA1;
    }
    for (int i = i0; i < i1; ++i) {
      int eC = eB;
      uint4 eaC = eaB, xC = xB, nC = nB;
      float4 sC0 = sB0, sC1 = sB1;
      if (i + 2 < i1) {
        LOADE(i + 2, eC, eaC, xC, nC, sC0, sC1);
      }
      // compute slot A
      unsigned short eh[8], xh[8], sh[8];
      unpack8(eaA, eh);
      unpack8(xA, xh);
      unpack8(nA, sh);
      float sv[8] = {sA0.x, sA0.y, sA0.z, sA0.w, sA1.x, sA1.y, sA1.z, sA1.w};
      unsigned short bh[8];
#pragma unroll
      for (int j = 0; j < 8; j++) {
        float ev = h2f(eh[j]);
        float sp = ev + nd[j] - m_p[j];
        float sr = ev + sv[j] - m_r[j];
        float ap = __expf(sp);
        float xe = h2f(xh[j]);
        z[j] += ap;
        z2[j] += ap * xe;
        float u = sr - sp;
        float evx = __expf(-fabsf(u));
        float wpos = 1.f / (1.f + evx);
        float wr = (u >= 0.f) ? wpos : 1.f - wpos;
        float xs_ = h2f(sh[j]);
        bh[j] = f2h(wr * xs_ + (1.f - wr) * xd[j]);
      }
      *(uint4*)(blendH + (size_t)eA * 1024 + octA(eA, o)) = pack8(bh);
      // rotate
      eA = eB; eaA = eaB; xA = xB; nA = nB; sA0 = sB0; sA1 = sB1;
      eB = eC; eaB = eaC; xB = xC; nB = nC; sB0 = sC0; sB1 = sC1;
    }
#undef LOADE
  }
  unsigned short zh[8];
#pragma unroll
  for (int j = 0; j < 8; j++) zh[j] = f2h(z2[j] / (z[j] + EPS));
  *(uint4*)(z2I + (size_t)n * 1024 + octA(n, o)) = pack8(zh);
}

// node_conf = nx @ Wnc ([512,55])
__global__ __launch_bounds__(256) void nodeconf_k(const float* __restrict__ nx,
                                                  const float* __restrict__ Wnc,
                                                  float* __restrict__ out) {
  int w = threadIdx.x >> 6, lane = threadIdx.x & 63;
  int n = blockIdx.x * 4 + w;
  const float* r = nx + (size_t)n * D;
  if (lane < 55) {
    float acc = 0.f;
    for (int k = 0; k < D; k++) acc = fmaf(r[k], Wnc[k * 55 + lane], acc);
    out[(size_t)n * 55 + lane] = acc;
  }
}

// edge_conf = ex @ Wec ([512,2]) — float4-vectorized
__global__ __launch_bounds__(256) void edgeconf_k(const float* __restrict__ ex,
                                                  const float* __restrict__ Wec,
                                                  float* __restrict__ out) {
  int w = threadIdx.x >> 6, lane = threadIdx.x & 63;
  int e = blockIdx.x * 4 + w;
  const float* r = ex + (size_t)e * D + lane * 8;
  float4 v0 = *(const float4*)r;
  float4 v1 = *(const float4*)(r + 4);
  const float* wp = Wec + lane * 16;
  float vv[8] = {v0.x, v0.y, v0.z, v0.w, v1.x, v1.y, v1.z, v1.w};
  float a0 = 0.f, a1 = 0.f;
#pragma unroll
  for (int j = 0; j < 8; j++) {
    a0 = fmaf(vv[j], wp[j * 2 + 0], a0);
    a1 = fmaf(vv[j], wp[j * 2 + 1], a1);
  }
#pragma unroll
  for (int off = 32; off; off >>= 1) {
    a0 += __shfl_down(a0, off);
    a1 += __shfl_down(a1, off);
  }
  if (lane == 0) { out[(size_t)e * 2 + 0] = a0; out[(size_t)e * 2 + 1] = a1; }
}

extern "C" void kernel_launch(void* const* d_in, const int* in_sizes, int n_in,
                              void* d_out, int out_size, void* d_ws, size_t ws_size,
                              hipStream_t stream) {
  const float* in_nx = (const float*)d_in[0];
  const float* in_ex = (const float*)d_in[1];
  const int* src = (const int*)d_in[2];
  const int* dst = (const int*)d_in[3];
  const float* Wa = (const float*)d_in[4];
  const float* Wn = (const float*)d_in[5];
  const float* We = (const float*)d_in[6];
  const float* Wnc = (const float*)d_in[7];
  const float* Wec = (const float*)d_in[8];

  float* out = (float*)d_out;
  float* o_nx = out;
  float* o_nc = o_nx + (size_t)NNODES * D;
  float* o_ex = o_nc + (size_t)NNODES * 55;
  float* o_ec = o_ex + (size_t)NEDGES * D;

  const size_t SZ_EH = (size_t)NEDGES * 1024;   // 80 MB fp16 edge rows
  const size_t SZ_NH = (size_t)NNODES * 1024;
  const size_t SZ_NF = (size_t)NNODES * 2048;
  const size_t MATSZ = (size_t)512 * 2048;      // 1 MB per weight mat (hi-only)
  char* w = (char*)d_ws;
  char* EaH = w;                                // fp16 Ea
  char* blendH = w + SZ_EH;                     // fp16 blend
  char* exA = w + 2 * SZ_EH;                    // exI ping
  char* nxA = w + 3 * SZ_EH;                    // nxI ping
  float* Na = (float*)(w + 3 * SZ_EH + SZ_NH);
  char* z2I = w + 3 * SZ_EH + SZ_NH + SZ_NF;
  float* mpf = (float*)(w + 3 * SZ_EH + 2 * SZ_NH + SZ_NF);  // [mp|mr]
  char* WT = w + 3 * SZ_EH + 2 * SZ_NH + SZ_NF + 8192;
  char* csr = WT + 15 * MATSZ;
  int* cnt = (int*)csr;
  int* offp = cnt + NNODES + 8;
  int* cur = offp + NNODES + 8;
  int* eid = cur + NNODES + 8;
  float* part_p = (float*)(eid + NEDGES);       // 625*512
  float* part_r = part_p + 625 * 512;
  float* part2 = part_r + 625 * 512;            // 5*1024

  char* exB = (char*)o_ex;   // fp16 ping inside f32 output regions
  char* nxB = (char*)o_nx;

  // one-time prep
  wprep_k<<<dim3(8, 16, 15), 256, 0, stream>>>(Wa, Wn, We, WT);
  toF16_k<<<2048, 256, 0, stream>>>(in_ex, exA, NEDGES * 64);
  toF16_k<<<2048, 256, 0, stream>>>(in_nx, nxA, NNODES * 64);
  hipMemsetAsync(cnt, 0, NNODES * sizeof(int), stream);
  hist_k<<<(NEDGES + 255) / 256, 256, 0, stream>>>(dst, cnt);
  scan_k<<<1, 256, 0, stream>>>(cnt, offp, cur);
  scatter_k<<<(NEDGES + 255) / 256, 256, 0, stream>>>(dst, cur, eid);

  dim3 gE(4, NEDGES / 128);           // (4, 625)
  dim3 gN(4, (NNODES + 127) / 128);   // (4, 79)

  for (int l = 0; l < LAYERS; l++) {
    const char* WaT = WT + (size_t)l * MATSZ;
    const char* WnT = WT + (size_t)(5 + l) * MATSZ;
    const char* WeT = WT + (size_t)(10 + l) * MATSZ;
    char* exCur = (l & 1) ? exB : exA;
    char* exNxt = (l & 1) ? exA : exB;
    char* nxCur = (l & 1) ? nxB : nxA;
    char* nxNxt = (l & 1) ? nxA : nxB;

    // Na = nx @ Wa_bot (f32), then EaH = fp16(ex @ Wa_top) with fused colmax
    gemmI<512, false, false, false><<<gN, 256, 0, stream>>>(
        nxCur, nullptr, WaT, 64, Na, NNODES, nullptr, nullptr, nullptr, nullptr, nullptr);
    gemmI<512, false, true, true><<<gE, 256, 0, stream>>>(
        exCur, nullptr, WaT, 0, EaH, NEDGES, src, dst, Na, part_p, part_r);

    colmax_red1_k<<<20, 256, 0, stream>>>(part_p, part2);
    colmax_red2_k<<<4, 256, 0, stream>>>(part2, mpf);

    aggblend_k<<<(NNODES + 3) / 4, 256, 0, stream>>>(EaH, Na, exCur, nxCur, src,
                                                     offp, eid, mpf, mpf + 512, blendH, z2I);

    // node update: nx' = act(concat(z2, nx) @ Wn)
    if (l < 4)
      gemmI<1024, true, true, false><<<gN, 256, 0, stream>>>(
          z2I, nxCur, WnT, 0, nxNxt, NNODES, nullptr, nullptr, nullptr, nullptr, nullptr);
    else
      gemmI<1024, true, false, false><<<gN, 256, 0, stream>>>(
          z2I, nxCur, WnT, 0, o_nx, NNODES, nullptr, nullptr, nullptr, nullptr, nullptr);

    // edge update: ex' = act(concat(blend, ex) @ We)
    if (l < 4)
      gemmI<1024, true, true, false><<<gE, 256, 0, stream>>>(
          blendH, exCur, WeT, 0, exNxt, NEDGES, nullptr, nullptr, nullptr, nullptr, nullptr);
    else
      gemmI<1024, true, false, false><<<gE, 256, 0, stream>>>(
          blendH, exCur, WeT, 0, o_ex, NEDGES, nullptr, nullptr, nullptr, nullptr, nullptr);
  }

  nodeconf_k<<<NNODES / 4, 256, 0, stream>>>(o_nx, Wnc, o_nc);
  edgeconf_k<<<NEDGES / 4, 256, 0, stream>>>(o_ex, Wec, o_ec);
}